// Round 1
// baseline (1863.761 us; speedup 1.0000x reference)
//
#include <hip/hip_runtime.h>

// ---------------- workspace offsets (in floats) ----------------
static constexpr size_t O_H0    = 0;          // 16384*256
static constexpr size_t O_H1P   = 4194304;    // 16384*78
static constexpr size_t O_X     = 5473216;    // 16384*156
static constexpr size_t O_A1    = 8029120;    // 512*1024
static constexpr size_t O_A2    = 8553408;
static constexpr size_t O_A3    = 9077696;
static constexpr size_t O_H4    = 9601984;    // 16384*156
static constexpr size_t O_H6    = 12157888;   // 16384*156
static constexpr size_t O_H1W2  = 14713792;   // 16384*312
static constexpr size_t O_H2    = 19825600;   // 16384*312
static constexpr size_t O_H2W3  = 24937408;   // 16384*624
static constexpr size_t O_H3    = 35161024;   // 16384*624
static constexpr size_t O_HG    = 45384640;   // 512*1092
static constexpr size_t O_FCG1O = 45943744;   // 512*1024
static constexpr size_t O_M     = 46468032;   // 3*3*26*96
static constexpr size_t O_F     = 46535424;   // 512*288
static constexpr size_t O_V     = 46682880;   // 512*128
static constexpr size_t O_XC    = 46748416;   // 512*256
static constexpr size_t O_FC1O  = 46879488;   // 512*1024
static constexpr size_t O_FC2O  = 47403776;   // 512*512
static constexpr size_t O_PART  = 47665920;   // 2*64*256
static constexpr size_t O_MV    = 47698688;   // 1024
static constexpr size_t O_BT21  = 47699712;   // 96*96*3
static constexpr size_t O_BT31  = 47727360;
static constexpr size_t O_W32T  = 47755008;   // end 47782656 floats = 191.1 MB
// aliases (sequentially dead regions reused):
static constexpr size_t O_XW1  = O_H0;             // after decoder done
static constexpr size_t O_H1   = O_X;              // after XW1 GEMM
static constexpr size_t O_H4W2 = O_H1W2;           // after h2 agg
static constexpr size_t O_H5   = O_H2W3;           // after h3 agg
static constexpr size_t O_R10  = O_H1W2;           // protein phase (after hg)
static constexpr size_t O_R20  = O_H1W2 + 1687296;
static constexpr size_t O_R30  = O_H1W2 + 3374592;
static constexpr size_t O_N21  = O_H2W3;           // protein phase (after hg)
static constexpr size_t O_N31  = O_H2W3 + 5061888;

// ---------------- generic tiled fp32 GEMM: C = A[M,K] @ B[K,N] (+bias)(+relu) ----------------
// AMODE 1: A row r is concat(z[r,0:64], x[r,0:78]) for the decoder input.
template<int AMODE, int ACT>
__global__ __launch_bounds__(256) void gemm_k(
    const float* __restrict__ A, const float* __restrict__ Bm,
    const float* __restrict__ bias, float* __restrict__ C,
    int M, int N, int K, const float* __restrict__ A2)
{
  __shared__ __align__(16) float sA[16 * 68];
  __shared__ __align__(16) float sB[16 * 68];
  const int tid = threadIdx.x;
  const int m0 = blockIdx.y * 64, n0 = blockIdx.x * 64;
  const int tx = tid & 15, ty = tid >> 4;
  float acc[4][4] = {};
  for (int k0 = 0; k0 < K; k0 += 16) {
#pragma unroll
    for (int s2 = 0; s2 < 4; s2++) {
      int idx = tid + s2 * 256;
      int am = idx >> 4, ak = idx & 15;
      int gm = m0 + am, gk = k0 + ak;
      float va = 0.f;
      if (gm < M && gk < K) {
        if (AMODE == 0) va = A[(size_t)gm * K + gk];
        else            va = (gk < 64) ? A[gm * 64 + gk] : A2[gm * 78 + gk - 64];
      }
      sA[ak * 68 + am] = va;
      int bk2 = idx >> 6, bn = idx & 63;
      int gk2 = k0 + bk2, gn = n0 + bn;
      float vb = 0.f;
      if (gk2 < K && gn < N) vb = Bm[(size_t)gk2 * N + gn];
      sB[bk2 * 68 + bn] = vb;
    }
    __syncthreads();
#pragma unroll
    for (int kk = 0; kk < 16; kk++) {
      const float4 a4 = *(const float4*)&sA[kk * 68 + ty * 4];
      const float4 b4 = *(const float4*)&sB[kk * 68 + tx * 4];
      const float ra[4] = {a4.x, a4.y, a4.z, a4.w};
      const float rb[4] = {b4.x, b4.y, b4.z, b4.w};
#pragma unroll
      for (int i2 = 0; i2 < 4; i2++)
#pragma unroll
        for (int j2 = 0; j2 < 4; j2++)
          acc[i2][j2] = fmaf(ra[i2], rb[j2], acc[i2][j2]);
    }
    __syncthreads();
  }
#pragma unroll
  for (int i2 = 0; i2 < 4; i2++) {
    int gm = m0 + ty * 4 + i2;
    if (gm >= M) continue;
#pragma unroll
    for (int j2 = 0; j2 < 4; j2++) {
      int gn = n0 + tx * 4 + j2;
      if (gn >= N) continue;
      float v = acc[i2][j2];
      if (bias) v += bias[gn];
      if (ACT == 1) v = fmaxf(v, 0.f);
      C[(size_t)gm * N + gn] = v;
    }
  }
}

// ---------------- BatchNorm (training batch stats over 16384 rows) ----------------
__global__ __launch_bounds__(256) void bn_partial(const float* __restrict__ H,
    float* __restrict__ PS, float* __restrict__ PQ, int C)
{
  int c = blockIdx.x * 64 + (threadIdx.x & 63);
  int rg = threadIdx.x >> 6;
  __shared__ float sS[256], sQ[256];
  float s = 0.f, q = 0.f;
  if (c < C) {
    int base = blockIdx.y * 256 + rg;
    for (int t = 0; t < 64; t++) {
      float v = H[(size_t)(base + 4 * t) * C + c];
      s += v; q += v * v;
    }
  }
  sS[threadIdx.x] = s; sQ[threadIdx.x] = q;
  __syncthreads();
  if (threadIdx.x < 64 && c < C) {
    float ts = sS[threadIdx.x] + sS[threadIdx.x + 64] + sS[threadIdx.x + 128] + sS[threadIdx.x + 192];
    float tq = sQ[threadIdx.x] + sQ[threadIdx.x + 64] + sQ[threadIdx.x + 128] + sQ[threadIdx.x + 192];
    PS[blockIdx.y * C + c] = ts;
    PQ[blockIdx.y * C + c] = tq;
  }
}

__global__ void bn_final(const float* __restrict__ PS, const float* __restrict__ PQ,
                         float* __restrict__ MV, int C)
{
  int c = threadIdx.x;
  if (c >= C) return;
  float s = 0.f, q = 0.f;
  for (int y = 0; y < 64; y++) { s += PS[y * C + c]; q += PQ[y * C + c]; }
  float mean = s * (1.f / 16384.f);
  float var = q * (1.f / 16384.f) - mean * mean;
  MV[c] = mean; MV[256 + c] = var;
}

// act: 1=relu, 2=tanh. out stride allows writing tanh directly into X[:, 0:78].
__global__ void bn_norm(const float* __restrict__ IN, float* __restrict__ OUT,
                        const float* __restrict__ MV, const float* __restrict__ g,
                        const float* __restrict__ bb, int C, int ostride, int total, int act)
{
  int idx = blockIdx.x * 256 + threadIdx.x;
  if (idx >= total) return;
  int r = idx / C, c = idx - r * C;
  float v = (IN[idx] - MV[c]) * (1.f / sqrtf(MV[256 + c] + 1e-5f)) * g[c] + bb[c];
  v = (act == 1) ? fmaxf(v, 0.f) : tanhf(v);
  OUT[(size_t)r * ostride + c] = v;
}

__global__ void xcopy_kernel(const float* __restrict__ x, float* __restrict__ X)
{
  int idx = blockIdx.x * 256 + threadIdx.x;
  if (idx >= 16384 * 78) return;
  int r = idx / 78, j = idx - r * 78;
  X[(size_t)r * 156 + 78 + j] = x[idx];
}

// ---------------- adjacency: A1/A2/A3 gcn_norm, one block per batch ----------------
__global__ __launch_bounds__(1024) void adj_kernel(const float* __restrict__ adj,
    float* __restrict__ A1o, float* __restrict__ A2o, float* __restrict__ A3o)
{
  int b = blockIdx.x, t = threadIdx.x;
  int i = t >> 5, j = t & 31;
  __shared__ float sA[32][33], sP[32][33];
  __shared__ float sd1[32], sd2[32], sd3[32];
  float a = adj[b * 1024 + t];
  sA[i][j] = a;
  float ah = (i == j) ? fmaxf(a, 1.f) : a;
  float rs = ah;
#pragma unroll
  for (int m = 16; m >= 1; m >>= 1) rs += __shfl_xor(rs, m, 32);
  float di = 1.f / sqrtf(rs);
  if (j == 0) sd1[i] = di;
  __syncthreads();
  A1o[b * 1024 + t] = ah * di * sd1[j];
  float c2 = 0.f;
#pragma unroll
  for (int k = 0; k < 32; k++) c2 += sA[i][k] * sA[k][j];
  float p2 = (c2 > 0.f) ? 1.f : 0.f;
  sP[i][j] = p2;
  float ah2 = (i == j) ? 1.f : p2;
  float rs2 = ah2;
#pragma unroll
  for (int m = 16; m >= 1; m >>= 1) rs2 += __shfl_xor(rs2, m, 32);
  float di2 = 1.f / sqrtf(rs2);
  if (j == 0) sd2[i] = di2;
  __syncthreads();
  A2o[b * 1024 + t] = ah2 * di2 * sd2[j];
  float c3 = 0.f;
#pragma unroll
  for (int k = 0; k < 32; k++) c3 += sP[i][k] * sA[k][j];
  float p3 = (c3 > 0.f) ? 1.f : 0.f;
  float ah3 = (i == j) ? 1.f : p3;
  float rs3 = ah3;
#pragma unroll
  for (int m = 16; m >= 1; m >>= 1) rs3 += __shfl_xor(rs3, m, 32);
  float di3 = 1.f / sqrtf(rs3);
  if (j == 0) sd3[i] = di3;
  __syncthreads();
  A3o[b * 1024 + t] = ah3 * di3 * sd3[j];
}

// ---------------- GCN aggregation: OUT[b,n,c] = relu(sum_m A[b,n,m]*HW[b,m,c] + bias[c]) ----------------
__global__ __launch_bounds__(64) void agg_kernel(const float* __restrict__ A,
    const float* __restrict__ HW, const float* __restrict__ bias,
    float* __restrict__ OUT, int C)
{
  int b = blockIdx.y;
  int c = blockIdx.x * 64 + threadIdx.x;
  __shared__ float sAd[1024];
  for (int e = threadIdx.x; e < 1024; e += 64) sAd[e] = A[b * 1024 + e];
  __syncthreads();
  if (c >= C) return;
  float hw[32];
  const float* hp = HW + (size_t)b * 32 * C + c;
#pragma unroll
  for (int m = 0; m < 32; m++) hw[m] = hp[(size_t)m * C];
  float bv = bias[c];
#pragma unroll 2
  for (int n = 0; n < 32; n++) {
    float s = bv;
#pragma unroll
    for (int m = 0; m < 32; m++) s = fmaf(sAd[n * 32 + m], hw[m], s);
    OUT[(size_t)b * 32 * C + (size_t)n * C + c] = fmaxf(s, 0.f);
  }
}

// ---------------- hg = max over 32 nodes of concat(h3,h5,h6) ----------------
__global__ void hg_kernel(const float* __restrict__ h3, const float* __restrict__ h5,
                          const float* __restrict__ h6, float* __restrict__ HG)
{
  int b = blockIdx.y;
  int c = blockIdx.x * 256 + threadIdx.x;
  if (c >= 1092) return;
  const float* p; int stride;
  if (c < 624)      { p = h3 + (size_t)b * 32 * 624 + c;          stride = 624; }
  else if (c < 936) { p = h5 + (size_t)b * 32 * 312 + (c - 624);  stride = 312; }
  else              { p = h6 + (size_t)b * 32 * 156 + (c - 936);  stride = 156; }
  float m = p[0];
#pragma unroll 4
  for (int n = 1; n < 32; n++) m = fmaxf(m, p[(size_t)n * stride]);
  HG[b * 1092 + c] = m;
}

// ---------------- attention: out = softmax(tanh(v), axis=1) * v  (128 features/row) ----------------
__global__ __launch_bounds__(64) void attn_kernel(const float* __restrict__ V,
    float* __restrict__ OUT, int ostride, int ooff)
{
  int r = blockIdx.x, lane = threadIdx.x;
  float v0 = V[r * 128 + lane], v1 = V[r * 128 + 64 + lane];
  float e0 = expf(tanhf(v0)), e1 = expf(tanhf(v1));
  float s = e0 + e1;
#pragma unroll
  for (int m = 32; m >= 1; m >>= 1) s += __shfl_xor(s, m);
  float inv = 1.f / s;
  OUT[r * ostride + ooff + lane] = e0 * inv * v0;
  OUT[r * ostride + ooff + 64 + lane] = e1 * inv * v1;
}

// ---------------- protein tables ----------------
// M[cv][k][tok][o] = sum_i emb[tok,i] * Wcv[o,i,k]  (layer-1 convs, in=128)
__global__ void mtable_kernel(const float* __restrict__ emb, const float* __restrict__ W10,
    const float* __restrict__ W20, const float* __restrict__ W30, float* __restrict__ M)
{
  int idx = blockIdx.x * 256 + threadIdx.x;
  if (idx >= 3 * 3 * 26 * 96) return;
  int o = idx % 96, tok = (idx / 96) % 26, k = (idx / (96 * 26)) % 3, cv = idx / (96 * 26 * 3);
  const float* W = (cv == 0) ? W10 : ((cv == 1) ? W20 : W30);
  float s = 0.f;
#pragma unroll 4
  for (int i = 0; i < 128; i++) s = fmaf(emb[tok * 128 + i], W[(o * 128 + i) * 3 + k], s);
  M[idx] = s;
}

// R[g][o] = relu(bias[o] + M0[t0][o] + M1[t1][o] + M2[t2][o]) for all 26^3 grams
__global__ void rtable_kernel(const float* __restrict__ M,
    const float* __restrict__ b1, const float* __restrict__ b2, const float* __restrict__ b3,
    float* __restrict__ R1, float* __restrict__ R2, float* __restrict__ R3)
{
  int cv = blockIdx.y;
  int idx = blockIdx.x * 256 + threadIdx.x;
  if (idx >= 17576 * 96) return;
  int o = idx % 96, g = idx / 96;
  int t0 = g / 676, t1 = (g / 26) % 26, t2 = g % 26;
  const float* Mc = M + cv * 3 * 26 * 96;
  float v = ((cv == 0) ? b1 : ((cv == 1) ? b2 : b3))[o];
  v += Mc[(0 * 26 + t0) * 96 + o] + Mc[(1 * 26 + t1) * 96 + o] + Mc[(2 * 26 + t2) * 96 + o];
  float* R = (cv == 0) ? R1 : ((cv == 1) ? R2 : R3);
  R[idx] = fmaxf(v, 0.f);
}

// weight transpose. mode 0: out[i*288 + k*96 + o] = W[o,i,k]  (GEMM B for N-tables)
//                  mode 1: out[(k*96+i)*96 + o] = W[o,i,k]    (conv3 weights)
__global__ void wtrans_kernel(const float* __restrict__ W, float* __restrict__ out, int mode)
{
  int e = blockIdx.x * 256 + threadIdx.x;
  if (e >= 96 * 96 * 3) return;
  int o, i, k;
  if (mode == 0) { i = e / 288; int r = e % 288; k = r / 96; o = r % 96; }
  else           { k = e / (96 * 96); i = (e / 96) % 96; o = e % 96; }
  out[e] = W[(o * 96 + i) * 3 + k];
}

// ---------------- f1/f2: max over positions of table-driven conv outputs ----------------
// NK=1: v = table[g(l)*96+o] (already biased+relu'd).  NK=3: v = relu(bias[o] + sum_k table[(g(l+k)*3+k)*96+o])
template<int NK>
__global__ __launch_bounds__(128) void fmax_scan(const int* __restrict__ target,
    const float* __restrict__ table, const float* __restrict__ bias,
    float* __restrict__ F, int Lout, int foff)
{
  int b = blockIdx.x;
  int tid = threadIdx.x;
  __shared__ int sG[998];
  int ngr = Lout + NK - 1;
  for (int p = tid; p < ngr; p += 128) {
    int t0 = target[b * 1000 + p];
    int t1 = target[b * 1000 + p + 1];
    int t2 = target[b * 1000 + p + 2];
    sG[p] = (t0 * 26 + t1) * 26 + t2;
  }
  __syncthreads();
  int o = tid;
  if (o >= 96) return;
  int chunk = (Lout + gridDim.y - 1) / gridDim.y;
  int l0 = blockIdx.y * chunk;
  int l1 = min(l0 + chunk, Lout);
  float m = 0.f;  // all candidates are >= 0 (post-relu)
  for (int l = l0; l < l1; l++) {
    float v;
    if (NK == 1) {
      v = table[(size_t)sG[l] * 96 + o];
    } else {
      v = bias[o];
#pragma unroll
      for (int k = 0; k < 3; k++) v += table[((size_t)sG[l + k] * 3 + k) * 96 + o];
      v = fmaxf(v, 0.f);
    }
    m = fmaxf(m, v);
  }
  atomicMax((unsigned int*)&F[b * 288 + foff + o], __float_as_uint(m));
}

// ---------------- conv3 (c32) direct: inputs reconstructed from N31 tables ----------------
__global__ __launch_bounds__(256) void conv3_kernel(const int* __restrict__ target,
    const float* __restrict__ N31, const float* __restrict__ b31,
    const float* __restrict__ W32t, const float* __restrict__ b32, float* __restrict__ F)
{
  int b = blockIdx.y, tile = blockIdx.x;
  int l0 = tile * 64;
  int tid = threadIdx.x;
  __shared__ float sIn[96 * 67];   // [i][c], pitch 67 (bank-conflict-free both phases)
  __shared__ int sG[68];
  int ncols = min(66, 996 - l0);   // layer-2 output columns needed
  int nouts = min(64, 994 - l0);   // conv3 outputs in this tile
  for (int p = tid; p < ncols + 2; p += 256) {
    int t0 = target[b * 1000 + l0 + p];
    int t1 = target[b * 1000 + l0 + p + 1];
    int t2 = target[b * 1000 + l0 + p + 2];
    sG[p] = (t0 * 26 + t1) * 26 + t2;
  }
  __syncthreads();
  for (int e = tid; e < 96 * ncols; e += 256) {
    int i = e % 96, c = e / 96;
    float v = b31[i]
            + N31[((size_t)sG[c]     * 3 + 0) * 96 + i]
            + N31[((size_t)sG[c + 1] * 3 + 1) * 96 + i]
            + N31[((size_t)sG[c + 2] * 3 + 2) * 96 + i];
    sIn[i * 67 + c] = fmaxf(v, 0.f);
  }
  __syncthreads();
  int wv = __builtin_amdgcn_readfirstlane(tid >> 6);  // wave id, forced scalar
  int lane = tid & 63;
  int obase = wv * 24;                                 // 24 contiguous out-channels per wave
  float acc[24];
#pragma unroll
  for (int jj = 0; jj < 24; jj++) acc[jj] = b32[obase + jj];
#pragma unroll 1
  for (int k = 0; k < 3; k++) {
#pragma unroll 4
    for (int i = 0; i < 96; i++) {
      float xv = sIn[i * 67 + lane + k];
      const float* wp = W32t + ((size_t)(k * 96 + i)) * 96 + obase;  // uniform addr -> s_loads
#pragma unroll
      for (int jj = 0; jj < 24; jj++) acc[jj] = fmaf(xv, wp[jj], acc[jj]);
    }
  }
  bool lok = lane < nouts;
#pragma unroll
  for (int jj = 0; jj < 24; jj++) {
    float v = lok ? fmaxf(acc[jj], 0.f) : 0.f;
#pragma unroll
    for (int m = 32; m >= 1; m >>= 1) v = fmaxf(v, __shfl_xor(v, m));
    if (lane == 0) atomicMax((unsigned int*)&F[b * 288 + 192 + obase + jj], __float_as_uint(v));
  }
}

// ---------------- final row-dot: out[r] = FC2O[r,:] . out_W + out_b ----------------
__global__ __launch_bounds__(256) void outdot_kernel(const float* __restrict__ X,
    const float* __restrict__ W, const float* __restrict__ bptr, float* __restrict__ out)
{
  int r = blockIdx.x * 4 + (threadIdx.x >> 6);
  int lane = threadIdx.x & 63;
  float s = 0.f;
  for (int j = lane; j < 512; j += 64) s = fmaf(X[(size_t)r * 512 + j], W[j], s);
#pragma unroll
  for (int m = 32; m >= 1; m >>= 1) s += __shfl_xor(s, m);
  if (lane == 0) out[r] = s + bptr[0];
}

// ---------------- host-side dispatch ----------------
static inline void gemm(hipStream_t st, int AMODE, int ACT,
                        const float* A, const float* B, const float* bias, float* C,
                        int M, int N, int K, const float* A2 = nullptr)
{
  dim3 g((N + 63) / 64, (M + 63) / 64), blk(256);
  if (AMODE == 0 && ACT == 0)      gemm_k<0, 0><<<g, blk, 0, st>>>(A, B, bias, C, M, N, K, A2);
  else if (AMODE == 0 && ACT == 1) gemm_k<0, 1><<<g, blk, 0, st>>>(A, B, bias, C, M, N, K, A2);
  else                             gemm_k<1, 0><<<g, blk, 0, st>>>(A, B, bias, C, M, N, K, A2);
}

extern "C" void kernel_launch(void* const* d_in, const int* in_sizes, int n_in,
                              void* d_out, int out_size, void* d_ws, size_t ws_size,
                              hipStream_t stream)
{
  (void)in_sizes; (void)n_in; (void)out_size; (void)ws_size;
  const float* x      = (const float*)d_in[0];
  const float* adj    = (const float*)d_in[1];
  const int*   target = (const int*)  d_in[2];
  const float* z      = (const float*)d_in[3];
  const float* dec_W0 = (const float*)d_in[4];
  const float* dec_b0 = (const float*)d_in[5];
  const float* dec_g0 = (const float*)d_in[6];
  const float* dec_be0= (const float*)d_in[7];
  const float* dec_W1 = (const float*)d_in[8];
  const float* dec_b1 = (const float*)d_in[9];
  const float* dec_g1 = (const float*)d_in[10];
  const float* dec_be1= (const float*)d_in[11];
  const float* gW1    = (const float*)d_in[12];
  const float* gb1    = (const float*)d_in[13];
  const float* gW2    = (const float*)d_in[14];
  const float* gb2    = (const float*)d_in[15];
  const float* gW3    = (const float*)d_in[16];
  const float* gb3    = (const float*)d_in[17];
  const float* fcg1_W = (const float*)d_in[18];
  const float* fcg1_b = (const float*)d_in[19];
  const float* fcg2_W = (const float*)d_in[20];
  const float* fcg2_b = (const float*)d_in[21];
  const float* emb    = (const float*)d_in[22];
  const float* c10_W  = (const float*)d_in[23];
  const float* c10_b  = (const float*)d_in[24];
  const float* c20_W  = (const float*)d_in[25];
  const float* c20_b  = (const float*)d_in[26];
  const float* c21_W  = (const float*)d_in[27];
  const float* c21_b  = (const float*)d_in[28];
  const float* c30_W  = (const float*)d_in[29];
  const float* c30_b  = (const float*)d_in[30];
  const float* c31_W  = (const float*)d_in[31];
  const float* c31_b  = (const float*)d_in[32];
  const float* c32_W  = (const float*)d_in[33];
  const float* c32_b  = (const float*)d_in[34];
  const float* prot_W = (const float*)d_in[35];
  const float* prot_b = (const float*)d_in[36];
  const float* fc1_W  = (const float*)d_in[37];
  const float* fc1_b  = (const float*)d_in[38];
  const float* fc2_W  = (const float*)d_in[39];
  const float* fc2_b  = (const float*)d_in[40];
  const float* out_W  = (const float*)d_in[41];
  const float* out_b  = (const float*)d_in[42];
  float* out = (float*)d_out;
  float* ws = (float*)d_ws;

  float* H0   = ws + O_H0;   float* H1P  = ws + O_H1P;  float* X    = ws + O_X;
  float* A1   = ws + O_A1;   float* A2   = ws + O_A2;   float* A3   = ws + O_A3;
  float* XW1  = ws + O_XW1;  float* H1   = ws + O_H1;   float* H4   = ws + O_H4;
  float* H6   = ws + O_H6;   float* H1W2 = ws + O_H1W2; float* H2   = ws + O_H2;
  float* H2W3 = ws + O_H2W3; float* H3   = ws + O_H3;   float* H4W2 = ws + O_H4W2;
  float* H5   = ws + O_H5;   float* HG   = ws + O_HG;   float* FCG1O= ws + O_FCG1O;
  float* Mt   = ws + O_M;    float* F    = ws + O_F;    float* V    = ws + O_V;
  float* XC   = ws + O_XC;   float* FC1O = ws + O_FC1O; float* FC2O = ws + O_FC2O;
  float* PS   = ws + O_PART; float* PQ   = ws + O_PART + 16384;
  float* MV   = ws + O_MV;
  float* R10  = ws + O_R10;  float* R20  = ws + O_R20;  float* R30  = ws + O_R30;
  float* N21  = ws + O_N21;  float* N31  = ws + O_N31;
  float* BT21 = ws + O_BT21; float* BT31 = ws + O_BT31; float* W32T = ws + O_W32T;

  // ---- decoder (frozen cVAE) ----
  gemm(stream, 1, 0, z, dec_W0, dec_b0, H0, 16384, 256, 142, x);
  bn_partial<<<dim3(4, 64), 256, 0, stream>>>(H0, PS, PQ, 256);
  bn_final<<<1, 256, 0, stream>>>(PS, PQ, MV, 256);
  bn_norm<<<16384, 256, 0, stream>>>(H0, H0, MV, dec_g0, dec_be0, 256, 256, 16384 * 256, 1);
  gemm(stream, 0, 0, H0, dec_W1, dec_b1, H1P, 16384, 78, 256);
  bn_partial<<<dim3(2, 64), 256, 0, stream>>>(H1P, PS, PQ, 78);
  bn_final<<<1, 256, 0, stream>>>(PS, PQ, MV, 78);
  bn_norm<<<4995, 256, 0, stream>>>(H1P, X, MV, dec_g1, dec_be1, 78, 156, 16384 * 78, 2);
  xcopy_kernel<<<4995, 256, 0, stream>>>(x, X);

  // ---- adjacency powers + gcn_norm ----
  adj_kernel<<<512, 1024, 0, stream>>>(adj, A1, A2, A3);

  // ---- GCN stack ----
  gemm(stream, 0, 0, X, gW1, nullptr, XW1, 16384, 156, 156);
  agg_kernel<<<dim3(3, 512), 64, 0, stream>>>(A1, XW1, gb1, H1, 156);
  agg_kernel<<<dim3(3, 512), 64, 0, stream>>>(A2, XW1, gb1, H4, 156);
  agg_kernel<<<dim3(3, 512), 64, 0, stream>>>(A3, XW1, gb1, H6, 156);
  gemm(stream, 0, 0, H1, gW2, nullptr, H1W2, 16384, 312, 156);
  agg_kernel<<<dim3(5, 512), 64, 0, stream>>>(A1, H1W2, gb2, H2, 312);
  gemm(stream, 0, 0, H2, gW3, nullptr, H2W3, 16384, 624, 312);
  agg_kernel<<<dim3(10, 512), 64, 0, stream>>>(A1, H2W3, gb3, H3, 624);
  gemm(stream, 0, 0, H4, gW2, nullptr, H4W2, 16384, 312, 156);
  agg_kernel<<<dim3(5, 512), 64, 0, stream>>>(A2, H4W2, gb2, H5, 312);
  hg_kernel<<<dim3(5, 512), 256, 0, stream>>>(H3, H5, H6, HG);

  // ---- graph head ----
  gemm(stream, 0, 1, HG, fcg1_W, fcg1_b, FCG1O, 512, 1024, 1092);
  gemm(stream, 0, 0, FCG1O, fcg2_W, fcg2_b, V, 512, 128, 1024);
  attn_kernel<<<512, 64, 0, stream>>>(V, XC, 256, 0);

  // ---- protein branch (tables overlay dead GCN regions; strictly after hg) ----
  hipMemsetAsync(F, 0, 512 * 288 * sizeof(float), stream);
  mtable_kernel<<<264, 256, 0, stream>>>(emb, c10_W, c20_W, c30_W, Mt);
  rtable_kernel<<<dim3(6591, 3), 256, 0, stream>>>(Mt, c10_b, c20_b, c30_b, R10, R20, R30);
  wtrans_kernel<<<108, 256, 0, stream>>>(c21_W, BT21, 0);
  wtrans_kernel<<<108, 256, 0, stream>>>(c31_W, BT31, 0);
  wtrans_kernel<<<108, 256, 0, stream>>>(c32_W, W32T, 1);
  gemm(stream, 0, 0, R20, BT21, nullptr, N21, 17576, 288, 96);
  gemm(stream, 0, 0, R30, BT31, nullptr, N31, 17576, 288, 96);
  fmax_scan<1><<<dim3(512, 8), 128, 0, stream>>>(target, R10, nullptr, F, 998, 0);
  fmax_scan<3><<<dim3(512, 8), 128, 0, stream>>>(target, N21, c21_b, F, 996, 96);
  conv3_kernel<<<dim3(16, 512), 256, 0, stream>>>(target, N31, c31_b, W32T, c32_b, F);
  gemm(stream, 0, 0, F, prot_W, prot_b, V, 512, 128, 288);
  attn_kernel<<<512, 64, 0, stream>>>(V, XC, 256, 128);

  // ---- final MLP ----
  gemm(stream, 0, 1, XC, fc1_W, fc1_b, FC1O, 512, 1024, 256);
  gemm(stream, 0, 1, FC1O, fc2_W, fc2_b, FC2O, 512, 512, 1024);
  outdot_kernel<<<128, 256, 0, stream>>>(FC2O, out_W, out_b, out);
}